// Round 1
// baseline (1639.493 us; speedup 1.0000x reference)
//
#include <hip/hip_runtime.h>
#include <math.h>

#define B_ 16
#define LC_ 512
#define LP_ 4096
#define H_ 128
#define HH_ (H_*H_)

// ---------------- GEMM128: Y[r][0..127] = act(X[r][:]@W + bias) ----------------
// 32 rows/block, 256 threads, each thread 4 rows x 4 cols. W (64KB) + Xs^T (16KB) in LDS.
template<bool TANH>
__global__ __launch_bounds__(256) void gemm128_k(const float* __restrict__ X,
                                                 const float* __restrict__ W,
                                                 const float* __restrict__ bias,
                                                 float* __restrict__ Y) {
    __shared__ float Ws[HH_];
    __shared__ float Xs[128 * 32];  // transposed [k][r]
    const int t = threadIdx.x;
    const long row0 = (long)blockIdx.x * 32;

    const float4* W4 = (const float4*)W;
    float4* Ws4 = (float4*)Ws;
#pragma unroll
    for (int j = 0; j < 16; ++j) Ws4[j * 256 + t] = W4[j * 256 + t];

    const float4* X4 = (const float4*)(X + row0 * H_);
#pragma unroll
    for (int j = 0; j < 4; ++j) {
        int idx = j * 256 + t;
        int r = idx >> 5, k4 = idx & 31;
        float4 v = X4[idx];
        Xs[(k4 * 4 + 0) * 32 + r] = v.x;
        Xs[(k4 * 4 + 1) * 32 + r] = v.y;
        Xs[(k4 * 4 + 2) * 32 + r] = v.z;
        Xs[(k4 * 4 + 3) * 32 + r] = v.w;
    }
    __syncthreads();

    const int cg = t & 31;   // cols cg*4..+3
    const int rg = t >> 5;   // rows rg*4..+3
    float acc[4][4] = {};
#pragma unroll 4
    for (int k = 0; k < 128; ++k) {
        float4 xv = ((const float4*)Xs)[k * 8 + rg];
        float4 wv = ((const float4*)Ws)[k * 32 + cg];
        float xr[4] = {xv.x, xv.y, xv.z, xv.w};
        float wr[4] = {wv.x, wv.y, wv.z, wv.w};
#pragma unroll
        for (int a = 0; a < 4; ++a)
#pragma unroll
            for (int c = 0; c < 4; ++c)
                acc[a][c] = fmaf(xr[a], wr[c], acc[a][c]);
    }

    float bv[4] = {0.f, 0.f, 0.f, 0.f};
    if (bias) {
        float4 bq = ((const float4*)bias)[cg];
        bv[0] = bq.x; bv[1] = bq.y; bv[2] = bq.z; bv[3] = bq.w;
    }
#pragma unroll
    for (int a = 0; a < 4; ++a) {
        float v0 = acc[a][0] + bv[0], v1 = acc[a][1] + bv[1];
        float v2 = acc[a][2] + bv[2], v3 = acc[a][3] + bv[3];
        if (TANH) { v0 = tanhf(v0); v1 = tanhf(v1); v2 = tanhf(v2); v3 = tanhf(v3); }
        float4 o; o.x = v0; o.y = v1; o.z = v2; o.w = v3;
        ((float4*)(Y + (row0 + rg * 4 + a) * H_))[cg] = o;
    }
}

// ------------- ctx GEMM: Y[b,r,:] = mask[b,r] * (X[b,r,:] @ Mw[b]) -------------
__global__ __launch_bounds__(256) void ctx_gemm_k(const float* __restrict__ Xall,
                                                  const float* __restrict__ Mall,
                                                  const int* __restrict__ mask,
                                                  float* __restrict__ Y, int rowsPerB) {
    __shared__ float Ws[HH_];
    __shared__ float Xs[128 * 32];
    const int t = threadIdx.x;
    const int b = blockIdx.y;
    const long row0 = (long)b * rowsPerB + (long)blockIdx.x * 32;
    const float* W = Mall + (size_t)b * HH_;

    const float4* W4 = (const float4*)W;
    float4* Ws4 = (float4*)Ws;
#pragma unroll
    for (int j = 0; j < 16; ++j) Ws4[j * 256 + t] = W4[j * 256 + t];

    const float4* X4 = (const float4*)(Xall + row0 * H_);
#pragma unroll
    for (int j = 0; j < 4; ++j) {
        int idx = j * 256 + t;
        int r = idx >> 5, k4 = idx & 31;
        float4 v = X4[idx];
        Xs[(k4 * 4 + 0) * 32 + r] = v.x;
        Xs[(k4 * 4 + 1) * 32 + r] = v.y;
        Xs[(k4 * 4 + 2) * 32 + r] = v.z;
        Xs[(k4 * 4 + 3) * 32 + r] = v.w;
    }
    __syncthreads();

    const int cg = t & 31;
    const int rg = t >> 5;
    float acc[4][4] = {};
#pragma unroll 4
    for (int k = 0; k < 128; ++k) {
        float4 xv = ((const float4*)Xs)[k * 8 + rg];
        float4 wv = ((const float4*)Ws)[k * 32 + cg];
        float xr[4] = {xv.x, xv.y, xv.z, xv.w};
        float wr[4] = {wv.x, wv.y, wv.z, wv.w};
#pragma unroll
        for (int a = 0; a < 4; ++a)
#pragma unroll
            for (int c = 0; c < 4; ++c)
                acc[a][c] = fmaf(xr[a], wr[c], acc[a][c]);
    }
#pragma unroll
    for (int a = 0; a < 4; ++a) {
        long row = row0 + rg * 4 + a;
        float sc = (float)mask[row];
        float4 o;
        o.x = acc[a][0] * sc; o.y = acc[a][1] * sc;
        o.z = acc[a][2] * sc; o.w = acc[a][3] * sc;
        ((float4*)(Y + row * H_))[cg] = o;
    }
}

// ---- accum_outer: out[b] += sum_k mask[b,k] * Xl[b,k,:]^T (outer) Yr[b,k,:] ----
// one block handles KCHUNK rows of k for one batch, 8x8 per thread, atomic epilogue.
template<int KCHUNK>
__global__ __launch_bounds__(256) void accum_outer_k(const float* __restrict__ Xl,
                                                     const float* __restrict__ Yr,
                                                     const int* __restrict__ mask,
                                                     float* __restrict__ out, int Kb) {
    __shared__ float Xs[32 * 128];
    __shared__ float Ys[32 * 128];
    const int t = threadIdx.x;
    const int b = blockIdx.y;
    const int k0 = blockIdx.x * KCHUNK;
    const int tr = t >> 4, tc = t & 15;
    float acc[8][8] = {};

    for (int ks = 0; ks < KCHUNK; ks += 32) {
        const float4* Xg = (const float4*)(Xl + ((size_t)b * Kb + k0 + ks) * H_);
        const float4* Yg = (const float4*)(Yr + ((size_t)b * Kb + k0 + ks) * H_);
#pragma unroll
        for (int j = 0; j < 4; ++j) {
            int idx = j * 256 + t;
            int r = idx >> 5;
            float mval = (float)mask[b * Kb + k0 + ks + r];
            float4 xv = Xg[idx];
            xv.x *= mval; xv.y *= mval; xv.z *= mval; xv.w *= mval;
            ((float4*)Xs)[idx] = xv;
            ((float4*)Ys)[idx] = Yg[idx];
        }
        __syncthreads();
#pragma unroll 2
        for (int k = 0; k < 32; ++k) {
            float4 xa = *(const float4*)(Xs + k * 128 + tr * 8);
            float4 xb = *(const float4*)(Xs + k * 128 + tr * 8 + 4);
            float4 ya = *(const float4*)(Ys + k * 128 + tc * 8);
            float4 yb = *(const float4*)(Ys + k * 128 + tc * 8 + 4);
            float xr[8] = {xa.x, xa.y, xa.z, xa.w, xb.x, xb.y, xb.z, xb.w};
            float yr[8] = {ya.x, ya.y, ya.z, ya.w, yb.x, yb.y, yb.z, yb.w};
#pragma unroll
            for (int i2 = 0; i2 < 8; ++i2)
#pragma unroll
                for (int j2 = 0; j2 < 8; ++j2)
                    acc[i2][j2] = fmaf(xr[i2], yr[j2], acc[i2][j2]);
        }
        __syncthreads();
    }
    float* ob = out + (size_t)b * HH_;
#pragma unroll
    for (int i2 = 0; i2 < 8; ++i2)
#pragma unroll
        for (int j2 = 0; j2 < 8; ++j2)
            atomicAdd(&ob[(tr * 8 + i2) * H_ + tc * 8 + j2], acc[i2][j2]);
}

// ---- vc[b] = M[b] @ Wac ; vp[b] = N[b] @ Wap (per-b 128x128 times vector) ----
__global__ void mv_k(const float* __restrict__ M, const float* __restrict__ N,
                     const float* __restrict__ Wac, const float* __restrict__ Wap,
                     float* __restrict__ vc, float* __restrict__ vp) {
    int b = blockIdx.x, t = threadIdx.x;
    const float* mat = (t < 128) ? (M + (size_t)b * HH_ + (size_t)t * H_)
                                 : (N + (size_t)b * HH_ + (size_t)(t - 128) * H_);
    const float* w = (t < 128) ? Wac : Wap;
    float acc = 0.f;
#pragma unroll 8
    for (int h = 0; h < H_; ++h) acc = fmaf(mat[h], w[h], acc);
    if (t < 128) vc[b * H_ + t] = acc;
    else         vp[b * H_ + (t - 128)] = acc;
}

// ---- logits[b,r] = mask[b,r] * (feat[b,r,:] . v[b]) + bias ----
__global__ void logits_k(const float* __restrict__ feat, const int* __restrict__ mask,
                         const float* __restrict__ v, const float* __restrict__ biasPtr,
                         float* __restrict__ out, int n) {
    int idx = blockIdx.x * blockDim.x + threadIdx.x;
    int b = idx / n;
    const float4* r4 = (const float4*)(feat + (size_t)idx * H_);
    const float4* v4 = (const float4*)(v + (size_t)b * H_);
    float acc = 0.f;
#pragma unroll
    for (int h4 = 0; h4 < 32; ++h4) {
        float4 a = r4[h4], c = v4[h4];
        acc = fmaf(a.x, c.x, acc); acc = fmaf(a.y, c.y, acc);
        acc = fmaf(a.z, c.z, acc); acc = fmaf(a.w, c.w, acc);
    }
    out[idx] = (float)mask[idx] * acc + biasPtr[0];
}

// ---- masked softmax, faithful: max over ALL, exp*mask, denom + 1e-6 ----
__global__ __launch_bounds__(256) void softmax_k(const float* __restrict__ logits,
                                                 const int* __restrict__ mask,
                                                 float* __restrict__ w, int n) {
    int b = blockIdx.x, t = threadIdx.x;
    const float* l = logits + (size_t)b * n;
    const int* mk = mask + (size_t)b * n;
    float* ww = w + (size_t)b * n;
    __shared__ float Es[4096];
    __shared__ float red[4];

    float mx = -1e30f;
    for (int q = t; q < n; q += 256) mx = fmaxf(mx, l[q]);
#pragma unroll
    for (int o = 32; o > 0; o >>= 1) mx = fmaxf(mx, __shfl_down(mx, o, 64));
    if ((t & 63) == 0) red[t >> 6] = mx;
    __syncthreads();
    float m = fmaxf(fmaxf(red[0], red[1]), fmaxf(red[2], red[3]));
    __syncthreads();

    float s = 0.f;
    for (int q = t; q < n; q += 256) {
        float e = __expf(l[q] - m) * (float)mk[q];
        Es[q] = e;
        s += e;
    }
#pragma unroll
    for (int o = 32; o > 0; o >>= 1) s += __shfl_down(s, o, 64);
    if ((t & 63) == 0) red[t >> 6] = s;
    __syncthreads();
    float denom = red[0] + red[1] + red[2] + red[3] + 1e-6f;
    for (int q = t; q < n; q += 256) ww[q] = Es[q] / denom;
}

// ---- pooled[b,h] += sum_{q in chunk} proj[b,q,h] * w[b,q] ----
__global__ void pool_k(const float* __restrict__ proj, const float* __restrict__ w,
                       float* __restrict__ out, int n, int chunk) {
    int b = blockIdx.x, h = threadIdx.x;
    int q0 = blockIdx.y * chunk;
    const float* pb = proj + ((size_t)b * n + q0) * H_;
    const float* wb = w + (size_t)b * n + q0;
    float acc = 0.f;
#pragma unroll 4
    for (int q = 0; q < chunk; ++q) acc = fmaf(pb[(size_t)q * H_ + h], wb[q], acc);
    atomicAdd(&out[b * H_ + h], acc);
}

// ---- final[b,h] = concat(pooled[0..2])[b,:] @ Wcomb + bcomb ----
__global__ void final_k(const float* __restrict__ pooled, const float* __restrict__ Wcomb,
                        const float* __restrict__ bcomb, float* __restrict__ out) {
    int b = blockIdx.x, h = threadIdx.x;
    float acc = bcomb[h];
#pragma unroll 4
    for (int j = 0; j < 3 * H_; ++j) {
        int lay = j >> 7, hh = j & 127;
        acc = fmaf(pooled[((size_t)lay * B_ + b) * H_ + hh], Wcomb[j * H_ + h], acc);
    }
    out[b * H_ + h] = acc;
}

extern "C" void kernel_launch(void* const* d_in, const int* in_sizes, int n_in,
                              void* d_out, int out_size, void* d_ws, size_t ws_size,
                              hipStream_t stream) {
    const float* comp_feat = (const float*)d_in[0];
    const int*   comp_mask = (const int*)d_in[1];
    const float* prot_feat = (const float*)d_in[2];
    const int*   prot_mask = (const int*)d_in[3];
    const float* Wc      = (const float*)d_in[4];
    const float* bc      = (const float*)d_in[5];
    const float* Wp      = (const float*)d_in[6];
    const float* bp      = (const float*)d_in[7];
    const float* Wbl     = (const float*)d_in[8];
    const float* Wac     = (const float*)d_in[9];
    const float* bac     = (const float*)d_in[10];
    const float* Wap     = (const float*)d_in[11];
    const float* bap     = (const float*)d_in[12];
    const float* Wcomb_c = (const float*)d_in[13];
    const float* bcomb_c = (const float*)d_in[14];
    const float* Wcomb_p = (const float*)d_in[15];
    const float* bcomb_p = (const float*)d_in[16];

    float* ws = (float*)d_ws;
    float* prot_proj = ws;                                   // 16*4096*128
    float* comp_proj = prot_proj + (size_t)B_ * LP_ * H_;    // 16*512*128
    float* comp_bil  = comp_proj + (size_t)B_ * LC_ * H_;    // 16*512*128
    float* Mbuf = comp_bil + (size_t)B_ * LC_ * H_;          // 16*128*128
    float* Nbuf = Mbuf + (size_t)B_ * HH_;                   // 16*128*128
    float* vc   = Nbuf + (size_t)B_ * HH_;                   // 16*128
    float* vp   = vc + B_ * H_;
    float* logc = vp + B_ * H_;                              // 16*512
    float* logp = logc + B_ * LC_;                           // 16*4096
    float* cw   = logp + B_ * LP_;                           // 16*512
    float* pw   = cw + B_ * LC_;                             // 16*4096
    float* cp   = pw + B_ * LP_;                             // 3*16*128
    float* pp   = cp + 3 * B_ * H_;                          // 3*16*128

    float* out_cf = (float*)d_out;
    float* out_pf = out_cf + B_ * H_;
    float* out_cc = out_pf + B_ * H_;
    float* out_pc = out_cc + (size_t)B_ * LC_ * H_;

    for (int i = 0; i < 3; ++i) {
        hipMemsetAsync(Mbuf, 0, 2 * (size_t)B_ * HH_ * sizeof(float), stream);
        hipMemsetAsync(cp + (size_t)i * B_ * H_, 0, (size_t)B_ * H_ * sizeof(float), stream);
        hipMemsetAsync(pp + (size_t)i * B_ * H_, 0, (size_t)B_ * H_ * sizeof(float), stream);

        gemm128_k<true><<<dim3(B_ * LP_ / 32), 256, 0, stream>>>(
            prot_feat, Wp + (size_t)i * HH_, bp + i * H_, prot_proj);
        gemm128_k<true><<<dim3(B_ * LC_ / 32), 256, 0, stream>>>(
            comp_feat, Wc + (size_t)i * HH_, bc + i * H_, comp_proj);
        gemm128_k<false><<<dim3(B_ * LC_ / 32), 256, 0, stream>>>(
            comp_proj, Wbl + (size_t)i * HH_, nullptr, comp_bil);

        accum_outer_k<128><<<dim3(LP_ / 128, B_), 256, 0, stream>>>(
            prot_proj, prot_proj, prot_mask, Mbuf, LP_);
        accum_outer_k<32><<<dim3(LC_ / 32, B_), 256, 0, stream>>>(
            comp_bil, comp_proj, comp_mask, Nbuf, LC_);

        mv_k<<<dim3(B_), 256, 0, stream>>>(Mbuf, Nbuf, Wac + i * H_, Wap + i * H_, vc, vp);

        logits_k<<<dim3(B_ * LC_ / 256), 256, 0, stream>>>(comp_bil, comp_mask, vc, bac + i, logc, LC_);
        logits_k<<<dim3(B_ * LP_ / 256), 256, 0, stream>>>(prot_proj, prot_mask, vp, bap + i, logp, LP_);

        softmax_k<<<dim3(B_), 256, 0, stream>>>(logc, comp_mask, cw, LC_);
        softmax_k<<<dim3(B_), 256, 0, stream>>>(logp, prot_mask, pw, LP_);

        pool_k<<<dim3(B_, 2), 128, 0, stream>>>(comp_proj, cw, cp + (size_t)i * B_ * H_, LC_, 256);
        pool_k<<<dim3(B_, 8), 128, 0, stream>>>(prot_proj, pw, pp + (size_t)i * B_ * H_, LP_, 512);

        if (i == 2) {
            ctx_gemm_k<<<dim3(LC_ / 32, B_), 256, 0, stream>>>(comp_bil, Mbuf, comp_mask, out_cc, LC_);
            ctx_gemm_k<<<dim3(LP_ / 32, B_), 256, 0, stream>>>(prot_proj, Nbuf, prot_mask, out_pc, LP_);
        }
    }

    final_k<<<dim3(B_), 128, 0, stream>>>(cp, Wcomb_c, bcomb_c, out_cf);
    final_k<<<dim3(B_), 128, 0, stream>>>(pp, Wcomb_p, bcomb_p, out_pf);
}

// Round 2
// 700.519 us; speedup vs baseline: 2.3404x; 2.3404x over previous
//
#include <hip/hip_runtime.h>
#include <math.h>

#define B_ 16
#define LC_ 512
#define LP_ 4096
#define H_ 128
#define HH_ (H_*H_)

typedef __attribute__((ext_vector_type(8))) short bf16x8;
typedef __attribute__((ext_vector_type(4))) float f32x4;

__device__ __forceinline__ unsigned short f2bf(float f) {
    union { float f; unsigned u; } v; v.f = f;
    unsigned r = (v.u + 0x7FFFu + ((v.u >> 16) & 1u)) >> 16;
    return (unsigned short)r;
}

__device__ __forceinline__ bf16x8 ldfrag(const short* Vt, int h, int k) {
    const unsigned long long* p = (const unsigned long long*)(Vt + h * 68 + k);
    union { bf16x8 v; unsigned long long q[2]; } u;
    u.q[0] = p[0]; u.q[1] = p[1];
    return u.v;
}

// stage 64 k-rows x 128 h of fp32 (optionally masked per-row) into h-major bf16
// LDS tile Vt[128][68]. 256 threads: t&31 -> h-group of 4, t>>5 -> k-quad.
__device__ __forceinline__ void stage64(const float* __restrict__ src,
                                        const int* __restrict__ maskrow,
                                        short* __restrict__ dst, int t) {
    const int m = t & 31, kq = t >> 5;
#pragma unroll
    for (int p = 0; p < 2; ++p) {
        const int kc = p * 32 + kq * 4;
        const float4* s4 = (const float4*)(src + (size_t)kc * H_);
        float4 r0 = s4[0 * 32 + m];
        float4 r1 = s4[1 * 32 + m];
        float4 r2 = s4[2 * 32 + m];
        float4 r3 = s4[3 * 32 + m];
        if (maskrow) {
            float m0 = (float)maskrow[kc + 0], m1 = (float)maskrow[kc + 1];
            float m2 = (float)maskrow[kc + 2], m3 = (float)maskrow[kc + 3];
            r0.x *= m0; r0.y *= m0; r0.z *= m0; r0.w *= m0;
            r1.x *= m1; r1.y *= m1; r1.z *= m1; r1.w *= m1;
            r2.x *= m2; r2.y *= m2; r2.z *= m2; r2.w *= m2;
            r3.x *= m3; r3.y *= m3; r3.z *= m3; r3.w *= m3;
        }
        float c0[4] = {r0.x, r0.y, r0.z, r0.w};
        float c1[4] = {r1.x, r1.y, r1.z, r1.w};
        float c2[4] = {r2.x, r2.y, r2.z, r2.w};
        float c3[4] = {r3.x, r3.y, r3.z, r3.w};
#pragma unroll
        for (int i = 0; i < 4; ++i) {
            unsigned long long v = (unsigned long long)f2bf(c0[i])
                                 | ((unsigned long long)f2bf(c1[i]) << 16)
                                 | ((unsigned long long)f2bf(c2[i]) << 32)
                                 | ((unsigned long long)f2bf(c3[i]) << 48);
            *(unsigned long long*)(dst + (size_t)(4 * m + i) * 68 + kc) = v;
        }
    }
}

// part[(slice*B+b)] (128x128 fp32) = sum over this slice's k of
//   (mask[k]*Xl[k,:])^T (outer) Yr[k,:]   via bf16 MFMA, fp32 accum.
// SAME=true: Yr==Xl (symmetric, mask folded once since mask is binary).
template<bool SAME>
__global__ __launch_bounds__(256) void syrk_mfma_k(const float* __restrict__ Xl,
                                                   const float* __restrict__ Yr,
                                                   const int* __restrict__ mask,
                                                   float* __restrict__ part,
                                                   int Kb, int rowsPerSlice) {
    extern __shared__ short smem[];
    short* Xt = smem;
    short* Yt = SAME ? smem : (smem + 128 * 68);
    const int t = threadIdx.x;
    const int b = blockIdx.y, slice = blockIdx.x;
    const int l = t & 63, w = t >> 6;
    const int qi = (w >> 1) * 64, qj = (w & 1) * 64;
    const int lm = l & 15, lk = (l >> 4) * 8, lr = (l >> 4) * 4;

    f32x4 acc[4][4] = {};
    const int chunks = rowsPerSlice >> 6;
    const size_t boff = (size_t)b * Kb;

    for (int c = 0; c < chunks; ++c) {
        const int kbase = slice * rowsPerSlice + c * 64;
        stage64(Xl + (boff + kbase) * H_, mask + boff + kbase, Xt, t);
        if (!SAME) stage64(Yr + (boff + kbase) * H_, nullptr, Yt, t);
        __syncthreads();
#pragma unroll
        for (int ks = 0; ks < 64; ks += 32) {
            bf16x8 af[4], bfr[4];
#pragma unroll
            for (int it = 0; it < 4; ++it) af[it] = ldfrag(Xt, qi + it * 16 + lm, ks + lk);
#pragma unroll
            for (int jt = 0; jt < 4; ++jt) bfr[jt] = ldfrag(Yt, qj + jt * 16 + lm, ks + lk);
#pragma unroll
            for (int it = 0; it < 4; ++it)
#pragma unroll
                for (int jt = 0; jt < 4; ++jt)
                    acc[it][jt] = __builtin_amdgcn_mfma_f32_16x16x32_bf16(
                        af[it], bfr[jt], acc[it][jt], 0, 0, 0);
        }
        __syncthreads();
    }

    float* pb = part + ((size_t)slice * B_ + b) * HH_;
#pragma unroll
    for (int it = 0; it < 4; ++it)
#pragma unroll
        for (int jt = 0; jt < 4; ++jt)
#pragma unroll
            for (int r = 0; r < 4; ++r)
                pb[(size_t)(qi + it * 16 + lr + r) * H_ + qj + jt * 16 + lm] = acc[it][jt][r];
}

// out[idx] = sum_s part[s][idx], idx over B*HH/4 float4s
__global__ __launch_bounds__(256) void reduce_k(const float4* __restrict__ part,
                                                float4* __restrict__ out, int slices) {
    const int idx = blockIdx.x * 256 + threadIdx.x;
    float4 a = part[idx];
    for (int s = 1; s < slices; ++s) {
        float4 v = part[(size_t)s * (B_ * HH_ / 4) + idx];
        a.x += v.x; a.y += v.y; a.z += v.z; a.w += v.w;
    }
    out[idx] = a;
}

// ---------------- GEMM128: Y[r][0..127] = act(X[r][:]@W + bias) ----------------
template<bool TANH>
__global__ __launch_bounds__(256) void gemm128_k(const float* __restrict__ X,
                                                 const float* __restrict__ W,
                                                 const float* __restrict__ bias,
                                                 float* __restrict__ Y) {
    __shared__ float Ws[HH_];
    __shared__ float Xs[128 * 32];  // transposed [k][r]
    const int t = threadIdx.x;
    const long row0 = (long)blockIdx.x * 32;

    const float4* W4 = (const float4*)W;
    float4* Ws4 = (float4*)Ws;
#pragma unroll
    for (int j = 0; j < 16; ++j) Ws4[j * 256 + t] = W4[j * 256 + t];

    const float4* X4 = (const float4*)(X + row0 * H_);
#pragma unroll
    for (int j = 0; j < 4; ++j) {
        int idx = j * 256 + t;
        int r = idx >> 5, k4 = idx & 31;
        float4 v = X4[idx];
        Xs[(k4 * 4 + 0) * 32 + r] = v.x;
        Xs[(k4 * 4 + 1) * 32 + r] = v.y;
        Xs[(k4 * 4 + 2) * 32 + r] = v.z;
        Xs[(k4 * 4 + 3) * 32 + r] = v.w;
    }
    __syncthreads();

    const int cg = t & 31;
    const int rg = t >> 5;
    float acc[4][4] = {};
#pragma unroll 4
    for (int k = 0; k < 128; ++k) {
        float4 xv = ((const float4*)Xs)[k * 8 + rg];
        float4 wv = ((const float4*)Ws)[k * 32 + cg];
        float xr[4] = {xv.x, xv.y, xv.z, xv.w};
        float wr[4] = {wv.x, wv.y, wv.z, wv.w};
#pragma unroll
        for (int a = 0; a < 4; ++a)
#pragma unroll
            for (int c = 0; c < 4; ++c)
                acc[a][c] = fmaf(xr[a], wr[c], acc[a][c]);
    }

    float bv[4] = {0.f, 0.f, 0.f, 0.f};
    if (bias) {
        float4 bq = ((const float4*)bias)[cg];
        bv[0] = bq.x; bv[1] = bq.y; bv[2] = bq.z; bv[3] = bq.w;
    }
#pragma unroll
    for (int a = 0; a < 4; ++a) {
        float v0 = acc[a][0] + bv[0], v1 = acc[a][1] + bv[1];
        float v2 = acc[a][2] + bv[2], v3 = acc[a][3] + bv[3];
        if (TANH) { v0 = tanhf(v0); v1 = tanhf(v1); v2 = tanhf(v2); v3 = tanhf(v3); }
        float4 o; o.x = v0; o.y = v1; o.z = v2; o.w = v3;
        ((float4*)(Y + (row0 + rg * 4 + a) * H_))[cg] = o;
    }
}

// ------------- ctx GEMM: Y[b,r,:] = mask[b,r] * (X[b,r,:] @ Mw[b]) -------------
__global__ __launch_bounds__(256) void ctx_gemm_k(const float* __restrict__ Xall,
                                                  const float* __restrict__ Mall,
                                                  const int* __restrict__ mask,
                                                  float* __restrict__ Y, int rowsPerB) {
    __shared__ float Ws[HH_];
    __shared__ float Xs[128 * 32];
    const int t = threadIdx.x;
    const int b = blockIdx.y;
    const long row0 = (long)b * rowsPerB + (long)blockIdx.x * 32;
    const float* W = Mall + (size_t)b * HH_;

    const float4* W4 = (const float4*)W;
    float4* Ws4 = (float4*)Ws;
#pragma unroll
    for (int j = 0; j < 16; ++j) Ws4[j * 256 + t] = W4[j * 256 + t];

    const float4* X4 = (const float4*)(Xall + row0 * H_);
#pragma unroll
    for (int j = 0; j < 4; ++j) {
        int idx = j * 256 + t;
        int r = idx >> 5, k4 = idx & 31;
        float4 v = X4[idx];
        Xs[(k4 * 4 + 0) * 32 + r] = v.x;
        Xs[(k4 * 4 + 1) * 32 + r] = v.y;
        Xs[(k4 * 4 + 2) * 32 + r] = v.z;
        Xs[(k4 * 4 + 3) * 32 + r] = v.w;
    }
    __syncthreads();

    const int cg = t & 31;
    const int rg = t >> 5;
    float acc[4][4] = {};
#pragma unroll 4
    for (int k = 0; k < 128; ++k) {
        float4 xv = ((const float4*)Xs)[k * 8 + rg];
        float4 wv = ((const float4*)Ws)[k * 32 + cg];
        float xr[4] = {xv.x, xv.y, xv.z, xv.w};
        float wr[4] = {wv.x, wv.y, wv.z, wv.w};
#pragma unroll
        for (int a = 0; a < 4; ++a)
#pragma unroll
            for (int c = 0; c < 4; ++c)
                acc[a][c] = fmaf(xr[a], wr[c], acc[a][c]);
    }
#pragma unroll
    for (int a = 0; a < 4; ++a) {
        long row = row0 + rg * 4 + a;
        float sc = (float)mask[row];
        float4 o;
        o.x = acc[a][0] * sc; o.y = acc[a][1] * sc;
        o.z = acc[a][2] * sc; o.w = acc[a][3] * sc;
        ((float4*)(Y + row * H_))[cg] = o;
    }
}

// ---- vc[b] = M[b] @ Wac ; vp[b] = N[b] @ Wap ----
__global__ void mv_k(const float* __restrict__ M, const float* __restrict__ N,
                     const float* __restrict__ Wac, const float* __restrict__ Wap,
                     float* __restrict__ vc, float* __restrict__ vp) {
    int b = blockIdx.x, t = threadIdx.x;
    const float* mat = (t < 128) ? (M + (size_t)b * HH_ + (size_t)t * H_)
                                 : (N + (size_t)b * HH_ + (size_t)(t - 128) * H_);
    const float* w = (t < 128) ? Wac : Wap;
    float acc = 0.f;
#pragma unroll 8
    for (int h = 0; h < H_; ++h) acc = fmaf(mat[h], w[h], acc);
    if (t < 128) vc[b * H_ + t] = acc;
    else         vp[b * H_ + (t - 128)] = acc;
}

// ---- logits[b,r] = mask[b,r] * (feat[b,r,:] . v[b]) + bias ----
__global__ void logits_k(const float* __restrict__ feat, const int* __restrict__ mask,
                         const float* __restrict__ v, const float* __restrict__ biasPtr,
                         float* __restrict__ out, int n) {
    int idx = blockIdx.x * blockDim.x + threadIdx.x;
    int b = idx / n;
    const float4* r4 = (const float4*)(feat + (size_t)idx * H_);
    const float4* v4 = (const float4*)(v + (size_t)b * H_);
    float acc = 0.f;
#pragma unroll
    for (int h4 = 0; h4 < 32; ++h4) {
        float4 a = r4[h4], c = v4[h4];
        acc = fmaf(a.x, c.x, acc); acc = fmaf(a.y, c.y, acc);
        acc = fmaf(a.z, c.z, acc); acc = fmaf(a.w, c.w, acc);
    }
    out[idx] = (float)mask[idx] * acc + biasPtr[0];
}

// ---- masked softmax, faithful: max over ALL, exp*mask, denom + 1e-6 ----
__global__ __launch_bounds__(256) void softmax_k(const float* __restrict__ logits,
                                                 const int* __restrict__ mask,
                                                 float* __restrict__ w, int n) {
    int b = blockIdx.x, t = threadIdx.x;
    const float* l = logits + (size_t)b * n;
    const int* mk = mask + (size_t)b * n;
    float* ww = w + (size_t)b * n;
    __shared__ float Es[4096];
    __shared__ float red[4];

    float mx = -1e30f;
    for (int q = t; q < n; q += 256) mx = fmaxf(mx, l[q]);
#pragma unroll
    for (int o = 32; o > 0; o >>= 1) mx = fmaxf(mx, __shfl_down(mx, o, 64));
    if ((t & 63) == 0) red[t >> 6] = mx;
    __syncthreads();
    float m = fmaxf(fmaxf(red[0], red[1]), fmaxf(red[2], red[3]));
    __syncthreads();

    float s = 0.f;
    for (int q = t; q < n; q += 256) {
        float e = __expf(l[q] - m) * (float)mk[q];
        Es[q] = e;
        s += e;
    }
#pragma unroll
    for (int o = 32; o > 0; o >>= 1) s += __shfl_down(s, o, 64);
    if ((t & 63) == 0) red[t >> 6] = s;
    __syncthreads();
    float denom = red[0] + red[1] + red[2] + red[3] + 1e-6f;
    for (int q = t; q < n; q += 256) ww[q] = Es[q] / denom;
}

// ---- pooled[b,h] += sum_{q in chunk} proj[b,q,h] * w[b,q] ----
__global__ void pool_k(const float* __restrict__ proj, const float* __restrict__ w,
                       float* __restrict__ out, int n, int chunk) {
    int b = blockIdx.x, h = threadIdx.x;
    int q0 = blockIdx.y * chunk;
    const float* pb = proj + ((size_t)b * n + q0) * H_;
    const float* wb = w + (size_t)b * n + q0;
    float acc = 0.f;
#pragma unroll 4
    for (int q = 0; q < chunk; ++q) acc = fmaf(pb[(size_t)q * H_ + h], wb[q], acc);
    atomicAdd(&out[b * H_ + h], acc);
}

// ---- final[b,h] = concat(pooled[0..2])[b,:] @ Wcomb + bcomb ----
__global__ void final_k(const float* __restrict__ pooled, const float* __restrict__ Wcomb,
                        const float* __restrict__ bcomb, float* __restrict__ out) {
    int b = blockIdx.x, h = threadIdx.x;
    float acc = bcomb[h];
#pragma unroll 4
    for (int j = 0; j < 3 * H_; ++j) {
        int lay = j >> 7, hh = j & 127;
        acc = fmaf(pooled[((size_t)lay * B_ + b) * H_ + hh], Wcomb[j * H_ + h], acc);
    }
    out[b * H_ + h] = acc;
}

extern "C" void kernel_launch(void* const* d_in, const int* in_sizes, int n_in,
                              void* d_out, int out_size, void* d_ws, size_t ws_size,
                              hipStream_t stream) {
    const float* comp_feat = (const float*)d_in[0];
    const int*   comp_mask = (const int*)d_in[1];
    const float* prot_feat = (const float*)d_in[2];
    const int*   prot_mask = (const int*)d_in[3];
    const float* Wc      = (const float*)d_in[4];
    const float* bc      = (const float*)d_in[5];
    const float* Wp      = (const float*)d_in[6];
    const float* bp      = (const float*)d_in[7];
    const float* Wbl     = (const float*)d_in[8];
    const float* Wac     = (const float*)d_in[9];
    const float* bac     = (const float*)d_in[10];
    const float* Wap     = (const float*)d_in[11];
    const float* bap     = (const float*)d_in[12];
    const float* Wcomb_c = (const float*)d_in[13];
    const float* bcomb_c = (const float*)d_in[14];
    const float* Wcomb_p = (const float*)d_in[15];
    const float* bcomb_p = (const float*)d_in[16];

    float* ws = (float*)d_ws;
    float* prot_proj = ws;                                   // 16*4096*128
    float* comp_proj = prot_proj + (size_t)B_ * LP_ * H_;    // 16*512*128
    float* comp_bil  = comp_proj + (size_t)B_ * LC_ * H_;    // 16*512*128
    float* Mbuf = comp_bil + (size_t)B_ * LC_ * H_;          // 16*128*128
    float* Nbuf = Mbuf + (size_t)B_ * HH_;                   // 16*128*128
    float* vc   = Nbuf + (size_t)B_ * HH_;                   // 16*128
    float* vp   = vc + B_ * H_;
    float* logc = vp + B_ * H_;                              // 16*512
    float* logp = logc + B_ * LC_;                           // 16*4096
    float* cw   = logp + B_ * LP_;                           // 16*512
    float* pw   = cw + B_ * LC_;                             // 16*4096
    float* cp   = pw + B_ * LP_;                             // 3*16*128
    float* pp   = cp + 3 * B_ * H_;                          // 3*16*128

    float* out_cf = (float*)d_out;
    float* out_pf = out_cf + B_ * H_;
    float* out_cc = out_pf + B_ * H_;
    float* out_pc = out_cc + (size_t)B_ * LC_ * H_;

    // out_pc (16*4096*128 fp32 = 33.5MB) doubles as the syrk partial buffer;
    // it is only written as real output at the very end of layer 2.
    float* part = out_pc;

    const int SLICES_P = 32;  // 4096/32 = 128 rows/slice -> 33.5MB partials (fits exactly)
    const int SLICES_C = 8;   // 512/8  = 64 rows/slice  -> 8.4MB partials

    for (int i = 0; i < 3; ++i) {
        hipMemsetAsync(cp + (size_t)i * B_ * H_, 0, (size_t)B_ * H_ * sizeof(float), stream);
        hipMemsetAsync(pp + (size_t)i * B_ * H_, 0, (size_t)B_ * H_ * sizeof(float), stream);

        gemm128_k<true><<<dim3(B_ * LP_ / 32), 256, 0, stream>>>(
            prot_feat, Wp + (size_t)i * HH_, bp + i * H_, prot_proj);
        gemm128_k<true><<<dim3(B_ * LC_ / 32), 256, 0, stream>>>(
            comp_feat, Wc + (size_t)i * HH_, bc + i * H_, comp_proj);
        gemm128_k<false><<<dim3(B_ * LC_ / 32), 256, 0, stream>>>(
            comp_proj, Wbl + (size_t)i * HH_, nullptr, comp_bil);

        // M = prot_proj^T diag(pm) prot_proj   (mask folded once: pm binary)
        syrk_mfma_k<true><<<dim3(SLICES_P, B_), 256, 128 * 68 * sizeof(short), stream>>>(
            prot_proj, prot_proj, prot_mask, part, LP_, LP_ / SLICES_P);
        reduce_k<<<dim3(B_ * HH_ / 4 / 256), 256, 0, stream>>>(
            (const float4*)part, (float4*)Mbuf, SLICES_P);

        // N = comp_bil^T diag(cm) comp_proj
        syrk_mfma_k<false><<<dim3(SLICES_C, B_), 256, 2 * 128 * 68 * sizeof(short), stream>>>(
            comp_bil, comp_proj, comp_mask, part, LC_, LC_ / SLICES_C);
        reduce_k<<<dim3(B_ * HH_ / 4 / 256), 256, 0, stream>>>(
            (const float4*)part, (float4*)Nbuf, SLICES_C);

        mv_k<<<dim3(B_), 256, 0, stream>>>(Mbuf, Nbuf, Wac + i * H_, Wap + i * H_, vc, vp);

        logits_k<<<dim3(B_ * LC_ / 256), 256, 0, stream>>>(comp_bil, comp_mask, vc, bac + i, logc, LC_);
        logits_k<<<dim3(B_ * LP_ / 256), 256, 0, stream>>>(prot_proj, prot_mask, vp, bap + i, logp, LP_);

        softmax_k<<<dim3(B_), 256, 0, stream>>>(logc, comp_mask, cw, LC_);
        softmax_k<<<dim3(B_), 256, 0, stream>>>(logp, prot_mask, pw, LP_);

        pool_k<<<dim3(B_, 2), 128, 0, stream>>>(comp_proj, cw, cp + (size_t)i * B_ * H_, LC_, 256);
        pool_k<<<dim3(B_, 8), 128, 0, stream>>>(prot_proj, pw, pp + (size_t)i * B_ * H_, LP_, 512);

        if (i == 2) {
            ctx_gemm_k<<<dim3(LC_ / 32, B_), 256, 0, stream>>>(comp_bil, Mbuf, comp_mask, out_cc, LC_);
            ctx_gemm_k<<<dim3(LP_ / 32, B_), 256, 0, stream>>>(prot_proj, Nbuf, prot_mask, out_pc, LP_);
        }
    }

    final_k<<<dim3(B_), 128, 0, stream>>>(cp, Wcomb_c, bcomb_c, out_cf);
    final_k<<<dim3(B_), 128, 0, stream>>>(pp, Wcomb_p, bcomb_p, out_pf);
}

// Round 3
// 700.518 us; speedup vs baseline: 2.3404x; 1.0000x over previous
//
#include <hip/hip_runtime.h>
#include <math.h>

#define B_ 16
#define LC_ 512
#define LP_ 4096
#define H_ 128
#define HH_ (H_*H_)

typedef __attribute__((ext_vector_type(8))) short bf16x8;
typedef __attribute__((ext_vector_type(4))) float f32x4;

__device__ __forceinline__ unsigned short f2bf(float f) {
    union { float f; unsigned u; } v; v.f = f;
    unsigned r = (v.u + 0x7FFFu + ((v.u >> 16) & 1u)) >> 16;
    return (unsigned short)r;
}

__device__ __forceinline__ bf16x8 ldfrag(const short* Vt, int h, int k) {
    const unsigned long long* p = (const unsigned long long*)(Vt + h * 68 + k);
    union { bf16x8 v; unsigned long long q[2]; } u;
    u.q[0] = p[0]; u.q[1] = p[1];
    return u.v;
}

// stage 64 k-rows x 128 h of fp32 (optionally masked per-row) into h-major bf16
// LDS tile Vt[128][68]. 256 threads: t&31 -> h-group of 4, t>>5 -> k-quad.
__device__ __forceinline__ void stage64(const float* __restrict__ src,
                                        const int* __restrict__ maskrow,
                                        short* __restrict__ dst, int t) {
    const int m = t & 31, kq = t >> 5;
#pragma unroll
    for (int p = 0; p < 2; ++p) {
        const int kc = p * 32 + kq * 4;
        const float4* s4 = (const float4*)(src + (size_t)kc * H_);
        float4 r0 = s4[0 * 32 + m];
        float4 r1 = s4[1 * 32 + m];
        float4 r2 = s4[2 * 32 + m];
        float4 r3 = s4[3 * 32 + m];
        if (maskrow) {
            float m0 = (float)maskrow[kc + 0], m1 = (float)maskrow[kc + 1];
            float m2 = (float)maskrow[kc + 2], m3 = (float)maskrow[kc + 3];
            r0.x *= m0; r0.y *= m0; r0.z *= m0; r0.w *= m0;
            r1.x *= m1; r1.y *= m1; r1.z *= m1; r1.w *= m1;
            r2.x *= m2; r2.y *= m2; r2.z *= m2; r2.w *= m2;
            r3.x *= m3; r3.y *= m3; r3.z *= m3; r3.w *= m3;
        }
        float c0[4] = {r0.x, r0.y, r0.z, r0.w};
        float c1[4] = {r1.x, r1.y, r1.z, r1.w};
        float c2[4] = {r2.x, r2.y, r2.z, r2.w};
        float c3[4] = {r3.x, r3.y, r3.z, r3.w};
#pragma unroll
        for (int i = 0; i < 4; ++i) {
            unsigned long long v = (unsigned long long)f2bf(c0[i])
                                 | ((unsigned long long)f2bf(c1[i]) << 16)
                                 | ((unsigned long long)f2bf(c2[i]) << 32)
                                 | ((unsigned long long)f2bf(c3[i]) << 48);
            *(unsigned long long*)(dst + (size_t)(4 * m + i) * 68 + kc) = v;
        }
    }
}

// part[(slice*B+b)] (128x128 fp32) = sum over this slice's k of
//   (mask[k]*Xl[k,:])^T (outer) Yr[k,:]   via bf16 MFMA, fp32 accum.
// SAME=true: Yr==Xl (symmetric, mask folded once since mask is binary).
template<bool SAME>
__global__ __launch_bounds__(256) void syrk_mfma_k(const float* __restrict__ Xl,
                                                   const float* __restrict__ Yr,
                                                   const int* __restrict__ mask,
                                                   float* __restrict__ part,
                                                   int Kb, int rowsPerSlice) {
    extern __shared__ short smem[];
    short* Xt = smem;
    short* Yt = SAME ? smem : (smem + 128 * 68);
    const int t = threadIdx.x;
    const int b = blockIdx.y, slice = blockIdx.x;
    const int l = t & 63, w = t >> 6;
    const int qi = (w >> 1) * 64, qj = (w & 1) * 64;
    const int lm = l & 15, lk = (l >> 4) * 8, lr = (l >> 4) * 4;

    f32x4 acc[4][4] = {};
    const int chunks = rowsPerSlice >> 6;
    const size_t boff = (size_t)b * Kb;

    for (int c = 0; c < chunks; ++c) {
        const int kbase = slice * rowsPerSlice + c * 64;
        stage64(Xl + (boff + kbase) * H_, mask + boff + kbase, Xt, t);
        if (!SAME) stage64(Yr + (boff + kbase) * H_, nullptr, Yt, t);
        __syncthreads();
#pragma unroll
        for (int ks = 0; ks < 64; ks += 32) {
            bf16x8 af[4], bfr[4];
#pragma unroll
            for (int it = 0; it < 4; ++it) af[it] = ldfrag(Xt, qi + it * 16 + lm, ks + lk);
#pragma unroll
            for (int jt = 0; jt < 4; ++jt) bfr[jt] = ldfrag(Yt, qj + jt * 16 + lm, ks + lk);
#pragma unroll
            for (int it = 0; it < 4; ++it)
#pragma unroll
                for (int jt = 0; jt < 4; ++jt)
                    acc[it][jt] = __builtin_amdgcn_mfma_f32_16x16x32_bf16(
                        af[it], bfr[jt], acc[it][jt], 0, 0, 0);
        }
        __syncthreads();
    }

    float* pb = part + ((size_t)slice * B_ + b) * HH_;
#pragma unroll
    for (int it = 0; it < 4; ++it)
#pragma unroll
        for (int jt = 0; jt < 4; ++jt)
#pragma unroll
            for (int r = 0; r < 4; ++r)
                pb[(size_t)(qi + it * 16 + lr + r) * H_ + qj + jt * 16 + lm] = acc[it][jt][r];
}

// out[idx] = sum_s part[s][idx], idx over B*HH/4 float4s
__global__ __launch_bounds__(256) void reduce_k(const float4* __restrict__ part,
                                                float4* __restrict__ out, int slices) {
    const int idx = blockIdx.x * 256 + threadIdx.x;
    float4 a = part[idx];
    for (int s = 1; s < slices; ++s) {
        float4 v = part[(size_t)s * (B_ * HH_ / 4) + idx];
        a.x += v.x; a.y += v.y; a.z += v.z; a.w += v.w;
    }
    out[idx] = a;
}

// ---------------- GEMM128: Y[r][0..127] = act(X[r][:]@W + bias) ----------------
template<bool TANH>
__global__ __launch_bounds__(256) void gemm128_k(const float* __restrict__ X,
                                                 const float* __restrict__ W,
                                                 const float* __restrict__ bias,
                                                 float* __restrict__ Y) {
    __shared__ float Ws[HH_];
    __shared__ float Xs[128 * 32];  // transposed [k][r]
    const int t = threadIdx.x;
    const long row0 = (long)blockIdx.x * 32;

    const float4* W4 = (const float4*)W;
    float4* Ws4 = (float4*)Ws;
#pragma unroll
    for (int j = 0; j < 16; ++j) Ws4[j * 256 + t] = W4[j * 256 + t];

    const float4* X4 = (const float4*)(X + row0 * H_);
#pragma unroll
    for (int j = 0; j < 4; ++j) {
        int idx = j * 256 + t;
        int r = idx >> 5, k4 = idx & 31;
        float4 v = X4[idx];
        Xs[(k4 * 4 + 0) * 32 + r] = v.x;
        Xs[(k4 * 4 + 1) * 32 + r] = v.y;
        Xs[(k4 * 4 + 2) * 32 + r] = v.z;
        Xs[(k4 * 4 + 3) * 32 + r] = v.w;
    }
    __syncthreads();

    const int cg = t & 31;
    const int rg = t >> 5;
    float acc[4][4] = {};
#pragma unroll 4
    for (int k = 0; k < 128; ++k) {
        float4 xv = ((const float4*)Xs)[k * 8 + rg];
        float4 wv = ((const float4*)Ws)[k * 32 + cg];
        float xr[4] = {xv.x, xv.y, xv.z, xv.w};
        float wr[4] = {wv.x, wv.y, wv.z, wv.w};
#pragma unroll
        for (int a = 0; a < 4; ++a)
#pragma unroll
            for (int c = 0; c < 4; ++c)
                acc[a][c] = fmaf(xr[a], wr[c], acc[a][c]);
    }

    float bv[4] = {0.f, 0.f, 0.f, 0.f};
    if (bias) {
        float4 bq = ((const float4*)bias)[cg];
        bv[0] = bq.x; bv[1] = bq.y; bv[2] = bq.z; bv[3] = bq.w;
    }
#pragma unroll
    for (int a = 0; a < 4; ++a) {
        float v0 = acc[a][0] + bv[0], v1 = acc[a][1] + bv[1];
        float v2 = acc[a][2] + bv[2], v3 = acc[a][3] + bv[3];
        if (TANH) { v0 = tanhf(v0); v1 = tanhf(v1); v2 = tanhf(v2); v3 = tanhf(v3); }
        float4 o; o.x = v0; o.y = v1; o.z = v2; o.w = v3;
        ((float4*)(Y + (row0 + rg * 4 + a) * H_))[cg] = o;
    }
}

// ------------- ctx GEMM: Y[b,r,:] = mask[b,r] * (X[b,r,:] @ Mw[b]) -------------
__global__ __launch_bounds__(256) void ctx_gemm_k(const float* __restrict__ Xall,
                                                  const float* __restrict__ Mall,
                                                  const int* __restrict__ mask,
                                                  float* __restrict__ Y, int rowsPerB) {
    __shared__ float Ws[HH_];
    __shared__ float Xs[128 * 32];
    const int t = threadIdx.x;
    const int b = blockIdx.y;
    const long row0 = (long)b * rowsPerB + (long)blockIdx.x * 32;
    const float* W = Mall + (size_t)b * HH_;

    const float4* W4 = (const float4*)W;
    float4* Ws4 = (float4*)Ws;
#pragma unroll
    for (int j = 0; j < 16; ++j) Ws4[j * 256 + t] = W4[j * 256 + t];

    const float4* X4 = (const float4*)(Xall + row0 * H_);
#pragma unroll
    for (int j = 0; j < 4; ++j) {
        int idx = j * 256 + t;
        int r = idx >> 5, k4 = idx & 31;
        float4 v = X4[idx];
        Xs[(k4 * 4 + 0) * 32 + r] = v.x;
        Xs[(k4 * 4 + 1) * 32 + r] = v.y;
        Xs[(k4 * 4 + 2) * 32 + r] = v.z;
        Xs[(k4 * 4 + 3) * 32 + r] = v.w;
    }
    __syncthreads();

    const int cg = t & 31;
    const int rg = t >> 5;
    float acc[4][4] = {};
#pragma unroll 4
    for (int k = 0; k < 128; ++k) {
        float4 xv = ((const float4*)Xs)[k * 8 + rg];
        float4 wv = ((const float4*)Ws)[k * 32 + cg];
        float xr[4] = {xv.x, xv.y, xv.z, xv.w};
        float wr[4] = {wv.x, wv.y, wv.z, wv.w};
#pragma unroll
        for (int a = 0; a < 4; ++a)
#pragma unroll
            for (int c = 0; c < 4; ++c)
                acc[a][c] = fmaf(xr[a], wr[c], acc[a][c]);
    }
#pragma unroll
    for (int a = 0; a < 4; ++a) {
        long row = row0 + rg * 4 + a;
        float sc = (float)mask[row];
        float4 o;
        o.x = acc[a][0] * sc; o.y = acc[a][1] * sc;
        o.z = acc[a][2] * sc; o.w = acc[a][3] * sc;
        ((float4*)(Y + row * H_))[cg] = o;
    }
}

// ---- vc[b] = M[b] @ Wac ; vp[b] = N[b] @ Wap ----
__global__ void mv_k(const float* __restrict__ M, const float* __restrict__ N,
                     const float* __restrict__ Wac, const float* __restrict__ Wap,
                     float* __restrict__ vc, float* __restrict__ vp) {
    int b = blockIdx.x, t = threadIdx.x;
    const float* mat = (t < 128) ? (M + (size_t)b * HH_ + (size_t)t * H_)
                                 : (N + (size_t)b * HH_ + (size_t)(t - 128) * H_);
    const float* w = (t < 128) ? Wac : Wap;
    float acc = 0.f;
#pragma unroll 8
    for (int h = 0; h < H_; ++h) acc = fmaf(mat[h], w[h], acc);
    if (t < 128) vc[b * H_ + t] = acc;
    else         vp[b * H_ + (t - 128)] = acc;
}

// ---- logits[b,r] = mask[b,r] * (feat[b,r,:] . v[b]) + bias ----
__global__ void logits_k(const float* __restrict__ feat, const int* __restrict__ mask,
                         const float* __restrict__ v, const float* __restrict__ biasPtr,
                         float* __restrict__ out, int n) {
    int idx = blockIdx.x * blockDim.x + threadIdx.x;
    int b = idx / n;
    const float4* r4 = (const float4*)(feat + (size_t)idx * H_);
    const float4* v4 = (const float4*)(v + (size_t)b * H_);
    float acc = 0.f;
#pragma unroll
    for (int h4 = 0; h4 < 32; ++h4) {
        float4 a = r4[h4], c = v4[h4];
        acc = fmaf(a.x, c.x, acc); acc = fmaf(a.y, c.y, acc);
        acc = fmaf(a.z, c.z, acc); acc = fmaf(a.w, c.w, acc);
    }
    out[idx] = (float)mask[idx] * acc + biasPtr[0];
}

// ---- masked softmax, faithful: max over ALL, exp*mask, denom + 1e-6 ----
__global__ __launch_bounds__(256) void softmax_k(const float* __restrict__ logits,
                                                 const int* __restrict__ mask,
                                                 float* __restrict__ w, int n) {
    int b = blockIdx.x, t = threadIdx.x;
    const float* l = logits + (size_t)b * n;
    const int* mk = mask + (size_t)b * n;
    float* ww = w + (size_t)b * n;
    __shared__ float Es[4096];
    __shared__ float red[4];

    float mx = -1e30f;
    for (int q = t; q < n; q += 256) mx = fmaxf(mx, l[q]);
#pragma unroll
    for (int o = 32; o > 0; o >>= 1) mx = fmaxf(mx, __shfl_down(mx, o, 64));
    if ((t & 63) == 0) red[t >> 6] = mx;
    __syncthreads();
    float m = fmaxf(fmaxf(red[0], red[1]), fmaxf(red[2], red[3]));
    __syncthreads();

    float s = 0.f;
    for (int q = t; q < n; q += 256) {
        float e = __expf(l[q] - m) * (float)mk[q];
        Es[q] = e;
        s += e;
    }
#pragma unroll
    for (int o = 32; o > 0; o >>= 1) s += __shfl_down(s, o, 64);
    if ((t & 63) == 0) red[t >> 6] = s;
    __syncthreads();
    float denom = red[0] + red[1] + red[2] + red[3] + 1e-6f;
    for (int q = t; q < n; q += 256) ww[q] = Es[q] / denom;
}

// ---- pooled[b,h] += sum_{q in chunk} proj[b,q,h] * w[b,q] ----
__global__ void pool_k(const float* __restrict__ proj, const float* __restrict__ w,
                       float* __restrict__ out, int n, int chunk) {
    int b = blockIdx.x, h = threadIdx.x;
    int q0 = blockIdx.y * chunk;
    const float* pb = proj + ((size_t)b * n + q0) * H_;
    const float* wb = w + (size_t)b * n + q0;
    float acc = 0.f;
#pragma unroll 4
    for (int q = 0; q < chunk; ++q) acc = fmaf(pb[(size_t)q * H_ + h], wb[q], acc);
    atomicAdd(&out[b * H_ + h], acc);
}

// ---- final[b,h] = concat(pooled[0..2])[b,:] @ Wcomb + bcomb ----
__global__ void final_k(const float* __restrict__ pooled, const float* __restrict__ Wcomb,
                        const float* __restrict__ bcomb, float* __restrict__ out) {
    int b = blockIdx.x, h = threadIdx.x;
    float acc = bcomb[h];
#pragma unroll 4
    for (int j = 0; j < 3 * H_; ++j) {
        int lay = j >> 7, hh = j & 127;
        acc = fmaf(pooled[((size_t)lay * B_ + b) * H_ + hh], Wcomb[j * H_ + h], acc);
    }
    out[b * H_ + h] = acc;
}

extern "C" void kernel_launch(void* const* d_in, const int* in_sizes, int n_in,
                              void* d_out, int out_size, void* d_ws, size_t ws_size,
                              hipStream_t stream) {
    const float* comp_feat = (const float*)d_in[0];
    const int*   comp_mask = (const int*)d_in[1];
    const float* prot_feat = (const float*)d_in[2];
    const int*   prot_mask = (const int*)d_in[3];
    const float* Wc      = (const float*)d_in[4];
    const float* bc      = (const float*)d_in[5];
    const float* Wp      = (const float*)d_in[6];
    const float* bp      = (const float*)d_in[7];
    const float* Wbl     = (const float*)d_in[8];
    const float* Wac     = (const float*)d_in[9];
    const float* bac     = (const float*)d_in[10];
    const float* Wap     = (const float*)d_in[11];
    const float* bap     = (const float*)d_in[12];
    const float* Wcomb_c = (const float*)d_in[13];
    const float* bcomb_c = (const float*)d_in[14];
    const float* Wcomb_p = (const float*)d_in[15];
    const float* bcomb_p = (const float*)d_in[16];

    float* ws = (float*)d_ws;
    float* prot_proj = ws;                                   // 16*4096*128
    float* comp_proj = prot_proj + (size_t)B_ * LP_ * H_;    // 16*512*128
    float* comp_bil  = comp_proj + (size_t)B_ * LC_ * H_;    // 16*512*128
    float* Mbuf = comp_bil + (size_t)B_ * LC_ * H_;          // 16*128*128
    float* Nbuf = Mbuf + (size_t)B_ * HH_;                   // 16*128*128
    float* vc   = Nbuf + (size_t)B_ * HH_;                   // 16*128
    float* vp   = vc + B_ * H_;
    float* logc = vp + B_ * H_;                              // 16*512
    float* logp = logc + B_ * LC_;                           // 16*4096
    float* cw   = logp + B_ * LP_;                           // 16*512
    float* pw   = cw + B_ * LC_;                             // 16*4096
    float* cp   = pw + B_ * LP_;                             // 3*16*128
    float* pp   = cp + 3 * B_ * H_;                          // 3*16*128

    float* out_cf = (float*)d_out;
    float* out_pf = out_cf + B_ * H_;
    float* out_cc = out_pf + B_ * H_;
    float* out_pc = out_cc + (size_t)B_ * LC_ * H_;

    // out_pc (16*4096*128 fp32 = 33.5MB) doubles as the syrk partial buffer;
    // it is only written as real output at the very end of layer 2.
    float* part = out_pc;

    const int SLICES_P = 32;  // 4096/32 = 128 rows/slice -> 33.5MB partials (fits exactly)
    const int SLICES_C = 8;   // 512/8  = 64 rows/slice  -> 8.4MB partials

    for (int i = 0; i < 3; ++i) {
        hipMemsetAsync(cp + (size_t)i * B_ * H_, 0, (size_t)B_ * H_ * sizeof(float), stream);
        hipMemsetAsync(pp + (size_t)i * B_ * H_, 0, (size_t)B_ * H_ * sizeof(float), stream);

        gemm128_k<true><<<dim3(B_ * LP_ / 32), 256, 0, stream>>>(
            prot_feat, Wp + (size_t)i * HH_, bp + i * H_, prot_proj);
        gemm128_k<true><<<dim3(B_ * LC_ / 32), 256, 0, stream>>>(
            comp_feat, Wc + (size_t)i * HH_, bc + i * H_, comp_proj);
        gemm128_k<false><<<dim3(B_ * LC_ / 32), 256, 0, stream>>>(
            comp_proj, Wbl + (size_t)i * HH_, nullptr, comp_bil);

        // M = prot_proj^T diag(pm) prot_proj   (mask folded once: pm binary)
        syrk_mfma_k<true><<<dim3(SLICES_P, B_), 256, 128 * 68 * sizeof(short), stream>>>(
            prot_proj, prot_proj, prot_mask, part, LP_, LP_ / SLICES_P);
        reduce_k<<<dim3(B_ * HH_ / 4 / 256), 256, 0, stream>>>(
            (const float4*)part, (float4*)Mbuf, SLICES_P);

        // N = comp_bil^T diag(cm) comp_proj
        syrk_mfma_k<false><<<dim3(SLICES_C, B_), 256, 2 * 128 * 68 * sizeof(short), stream>>>(
            comp_bil, comp_proj, comp_mask, part, LC_, LC_ / SLICES_C);
        reduce_k<<<dim3(B_ * HH_ / 4 / 256), 256, 0, stream>>>(
            (const float4*)part, (float4*)Nbuf, SLICES_C);

        mv_k<<<dim3(B_), 256, 0, stream>>>(Mbuf, Nbuf, Wac + i * H_, Wap + i * H_, vc, vp);

        logits_k<<<dim3(B_ * LC_ / 256), 256, 0, stream>>>(comp_bil, comp_mask, vc, bac + i, logc, LC_);
        logits_k<<<dim3(B_ * LP_ / 256), 256, 0, stream>>>(prot_proj, prot_mask, vp, bap + i, logp, LP_);

        softmax_k<<<dim3(B_), 256, 0, stream>>>(logc, comp_mask, cw, LC_);
        softmax_k<<<dim3(B_), 256, 0, stream>>>(logp, prot_mask, pw, LP_);

        pool_k<<<dim3(B_, 2), 128, 0, stream>>>(comp_proj, cw, cp + (size_t)i * B_ * H_, LC_, 256);
        pool_k<<<dim3(B_, 8), 128, 0, stream>>>(prot_proj, pw, pp + (size_t)i * B_ * H_, LP_, 512);

        if (i == 2) {
            ctx_gemm_k<<<dim3(LC_ / 32, B_), 256, 0, stream>>>(comp_bil, Mbuf, comp_mask, out_cc, LC_);
            ctx_gemm_k<<<dim3(LP_ / 32, B_), 256, 0, stream>>>(prot_proj, Nbuf, prot_mask, out_pc, LP_);
        }
    }

    final_k<<<dim3(B_), 128, 0, stream>>>(cp, Wcomb_c, bcomb_c, out_cf);
    final_k<<<dim3(B_), 128, 0, stream>>>(pp, Wcomb_p, bcomb_p, out_pf);
}